// Round 1
// baseline (173.483 us; speedup 1.0000x reference)
//
#include <hip/hip_runtime.h>

#define FRAME 160
#define KFR 15
#define ORDER 12
#define NFRAMES (4096 * KFR)

__device__ __forceinline__ float wred(float v) {
#pragma unroll
    for (int m = 1; m < 64; m <<= 1) v += __shfl_xor(v, m, 64);
    return v;
}

__global__ __launch_bounds__(256) void ResidualEmbedding_70798240907390_kernel(
    const int* __restrict__ bits, const float* __restrict__ pcm,
    const float* __restrict__ alpha_p, float* __restrict__ out)
{
    const int wave = threadIdx.x >> 6;
    const int lane = threadIdx.x & 63;
    const int f_id = blockIdx.x * 4 + wave;
    __shared__ float s_frame[4][FRAME];

    // Stage raw frame (coalesced per wave: 160 contiguous floats).
    const float* xg = pcm + (size_t)f_id * FRAME;
    s_frame[wave][lane]      = xg[lane];
    s_frame[wave][lane + 64] = xg[lane + 64];
    if (lane < 32) s_frame[wave][lane + 128] = xg[lane + 128];
    __syncthreads();

    // Blocked layout: lane l owns current-indices 3l..3l+2 of f/b (len 159).
    const int idx0 = lane * 3;
    const float w2p = 6.2831853071795864769f / 159.0f;  // hanning(160): 2*pi/(M-1)

    float F[3], Bv[3];
    float dpart = 0.0f;
#pragma unroll
    for (int t = 0; t < 3; ++t) {
        int idx = idx0 + t;
        if (idx < FRAME - 1) {
            float wb = 0.5f - 0.5f * __cosf(w2p * (float)idx);
            float wf = 0.5f - 0.5f * __cosf(w2p * (float)(idx + 1));
            float b0 = s_frame[wave][idx] * wb;       // b = xw[:-1]
            float f0 = s_frame[wave][idx + 1] * wf;   // f = xw[1:]
            F[t] = f0; Bv[t] = b0;
            dpart += f0 * f0 + b0 * b0;
        } else { F[t] = 0.0f; Bv[t] = 0.0f; }
    }
    float den = wred(dpart);

    // LPC coeffs: one per lane (lanes 0..12 hold a[0..12]).
    float a = (lane == 0) ? 1.0f : 0.0f;
    int Lc = FRAME - 1;

#pragma unroll
    for (int i = 0; i < ORDER; ++i) {
        // reflect = -2 * sum(b*f) / den  over current valid length Lc
        float p = 0.0f;
#pragma unroll
        for (int t = 0; t < 3; ++t) {
            int idx = idx0 + t;
            p += (idx < Lc) ? F[t] * Bv[t] : 0.0f;
        }
        float num = wred(p);
        float r = -2.0f * num / den;

        // a[:i+2] += r * a[:i+2][::-1]   (rev via per-lane bpermute)
        int src = i + 1 - lane;
        float arev = __shfl(a, src < 0 ? 0 : src, 64);
        if (lane <= i + 1) a += r * arev;

        // f += r*b ; b += r*f_old
        float nF[3], nB[3];
#pragma unroll
        for (int t = 0; t < 3; ++t) {
            nF[t] = fmaf(r, Bv[t], F[t]);
            nB[t] = fmaf(r, F[t], Bv[t]);
        }

        // den = (1-r^2)*den - b_new[-1]^2 - f_new[0]^2
        int le = Lc - 1;            // compile-time (loop fully unrolled)
        int sl = le / 3;
        int sr = le - sl * 3;
        float bl = (sr == 0) ? nB[0] : ((sr == 1) ? nB[1] : nB[2]);
        float blast  = __shfl(bl, sl, 64);
        float ffirst = __shfl(nF[0], 0, 64);
        den = (1.0f - r * r) * den - blast * blast - ffirst * ffirst;

        // f = f_new[1:] -> shift left by one (cross-lane for reg2);
        // b = b_new[:-1] -> handled by shrinking Lc mask (stale entries masked).
        float up = __shfl_down(nF[0], 1, 64);
        F[0] = nF[1]; F[1] = nF[2]; F[2] = up;
#pragma unroll
        for (int t = 0; t < 3; ++t) Bv[t] = nB[t];
        Lc -= 1;
    }

    // Broadcast a[0..12] to every lane.
    float ak[ORDER + 1];
#pragma unroll
    for (int k = 0; k <= ORDER; ++k) ak[k] = __shfl(a, k, 64);

    // Register window of raw frame: xr[j] = frame[3l - 12 + j], j=0..14.
    float xr[15];
#pragma unroll
    for (int j = 0; j < 15; ++j) {
        int m = idx0 - ORDER + j;
        xr[j] = (m >= 0 && m < FRAME) ? s_frame[wave][m] : 0.0f;
    }

    const float alpha = alpha_p[0];
    const float chip = 2.0f * (float)bits[f_id] - 1.0f;
    const float ac = alpha * chip;
    float* og = out + (size_t)f_id * FRAME;
#pragma unroll
    for (int t = 0; t < 3; ++t) {
        int n = idx0 + t;
        if (n < FRAME) {
            float acc = 0.0f;
#pragma unroll
            for (int k = 0; k <= ORDER; ++k)
                acc = fmaf(ak[k], xr[ORDER + t - k], acc);  // res[n] = sum a[k]*x[n-k]
            og[n] = fmaf(ac, acc, xr[ORDER + t]);           // pcm + alpha*res*chip
        }
    }
}

extern "C" void kernel_launch(void* const* d_in, const int* in_sizes, int n_in,
                              void* d_out, int out_size, void* d_ws, size_t ws_size,
                              hipStream_t stream) {
    const int*   bits  = (const int*)d_in[0];
    const float* pcm   = (const float*)d_in[1];
    const float* alpha = (const float*)d_in[2];
    float*       out   = (float*)d_out;

    // 61440 frames, one wave each, 4 waves per 256-thread block.
    dim3 grid(NFRAMES / 4), block(256);
    hipLaunchKernelGGL(ResidualEmbedding_70798240907390_kernel, grid, block, 0, stream,
                       bits, pcm, alpha, out);
}

// Round 2
// 110.453 us; speedup vs baseline: 1.5707x; 1.5707x over previous
//
#include <hip/hip_runtime.h>

#define FRAME 160
#define KFR 15
#define ORDER 12
#define NFRAMES (4096 * KFR)
#define EPL 10   // elements per lane
#define FPW 4    // frames per wave (16 lanes each)

// Reduce across a 16-lane group (xor masks < 16 stay in-group).
__device__ __forceinline__ float gred16(float v) {
#pragma unroll
    for (int m = 1; m < 16; m <<= 1) v += __shfl_xor(v, m, 64);
    return v;
}

__global__ __launch_bounds__(256) void ResidualEmbedding_70798240907390_kernel(
    const int* __restrict__ bits, const float* __restrict__ pcm,
    const float* __restrict__ alpha_p, float* __restrict__ out)
{
    const int wave = threadIdx.x >> 6;
    const int lane = threadIdx.x & 63;
    const int g    = lane >> 4;    // frame group within wave
    const int s    = lane & 15;    // sub-lane within group
    const int wf0  = (blockIdx.x * 4 + wave) * FPW;   // first frame of this wave
    const int f_id = wf0 + g;

    __shared__ float s_frame[4][FPW][FRAME];   // 10 KB

    // Stage 4 frames/wave = 640 floats = 160 float4, coalesced.
    {
        const float4* src = (const float4*)(pcm + (size_t)wf0 * FRAME);
        float4* dst = (float4*)&s_frame[wave][0][0];
        dst[lane]      = src[lane];
        dst[lane + 64] = src[lane + 64];
        if (lane < 32) dst[lane + 128] = src[lane + 128];
    }
    __syncthreads();
    const float* xf = &s_frame[wave][g][0];

    const int p0 = s * EPL;                    // this lane's base position
    const float w2p = 6.2831853071795864769f / 159.0f;   // hanning(160)

    // f[p] = xw[p+1], b[p] = xw[p], p = 0..158; pos 159 zeroed (invariant).
    float F[EPL], B[EPL];
    float dpart = 0.0f;
    float wprev = 0.5f - 0.5f * __cosf(w2p * (float)p0);
#pragma unroll
    for (int t = 0; t < EPL; ++t) {
        int p = p0 + t;
        float wnext = 0.5f - 0.5f * __cosf(w2p * (float)(p + 1));
        if (p < FRAME - 1) {
            float b0 = xf[p] * wprev;
            float f0 = xf[p + 1] * wnext;
            F[t] = f0; B[t] = b0;
            dpart += f0 * f0 + b0 * b0;
        } else { F[t] = 0.0f; B[t] = 0.0f; }
        wprev = wnext;
    }
    float den = gred16(dpart);

    // LPC coeffs: sub-lanes 0..12 of each group hold a[0..12].
    float a = (s == 0) ? 1.0f : 0.0f;

#pragma unroll
    for (int i = 0; i < ORDER; ++i) {
        // reflect = -2*sum(f*b)/den ; invalid tail positions are zero (no masks)
        float p = 0.0f;
#pragma unroll
        for (int t = 0; t < EPL; ++t) p = fmaf(F[t], B[t], p);
        float num = gred16(p);
        float r = -2.0f * num / den;

        // a[:i+2] += r * a[:i+2][::-1]
        int rs = i + 1 - s;
        float arev = __shfl(a, g * 16 + (rs < 0 ? 0 : rs), 64);
        if (s <= i + 1) a = fmaf(r, arev, a);

        // f += r*b ; b += r*f_old
        float nF[EPL], nB[EPL];
#pragma unroll
        for (int t = 0; t < EPL; ++t) {
            nF[t] = fmaf(r, B[t], F[t]);
            nB[t] = fmaf(r, F[t], B[t]);
        }

        // den = (1-r^2)*den - b_new[-1]^2 - f_new[0]^2
        const int pe = 158 - i;            // compile-time (full unroll)
        const int SL = pe / EPL, SS = pe % EPL;
        float blast  = __shfl(nB[SS], g * 16 + SL, 64);
        float ffirst = __shfl(nF[0], g * 16, 64);
        den = (1.0f - r * r) * den - blast * blast - ffirst * ffirst;

        // f = f_new[1:]  (shift left across lane registers, in-group)
        float up = __shfl_down(nF[0], 1, 16);
#pragma unroll
        for (int t = 0; t < EPL - 1; ++t) F[t] = nF[t + 1];
        F[EPL - 1] = (s == 15) ? 0.0f : up;
        // b = b_new[:-1]  (zero the newly-invalid tail slot -> keeps invariant)
#pragma unroll
        for (int t = 0; t < EPL; ++t) B[t] = nB[t];
        if (s == SL) B[SS] = 0.0f;
    }

    // Broadcast a[0..12] within the group.
    float ak[ORDER + 1];
#pragma unroll
    for (int k = 0; k <= ORDER; ++k) ak[k] = __shfl(a, g * 16 + k, 64);

    // Raw-sample window: xr[j] = x[p0 - 12 + j], j = 0..21.
    float xr[EPL + ORDER];
#pragma unroll
    for (int j = 0; j < EPL + ORDER; ++j) {
        int m = p0 - ORDER + j;
        xr[j] = (m >= 0) ? xf[m] : 0.0f;   // m <= p0+9 <= 159, always in range
    }

    const float ac = alpha_p[0] * (2.0f * (float)bits[f_id] - 1.0f);
    float res[EPL];
#pragma unroll
    for (int t = 0; t < EPL; ++t) {
        float acc = 0.0f;
#pragma unroll
        for (int k = 0; k <= ORDER; ++k)
            acc = fmaf(ak[k], xr[ORDER + t - k], acc);   // res[n] = sum a[k]*x[n-k]
        res[t] = fmaf(ac, acc, xr[ORDER + t]);           // pcm + alpha*res*chip
    }
    float2* og = (float2*)(out + (size_t)f_id * FRAME + p0);  // 8B-aligned (p0*4 = 40s)
#pragma unroll
    for (int t = 0; t < EPL / 2; ++t)
        og[t] = make_float2(res[2 * t], res[2 * t + 1]);
}

extern "C" void kernel_launch(void* const* d_in, const int* in_sizes, int n_in,
                              void* d_out, int out_size, void* d_ws, size_t ws_size,
                              hipStream_t stream) {
    const int*   bits  = (const int*)d_in[0];
    const float* pcm   = (const float*)d_in[1];
    const float* alpha = (const float*)d_in[2];
    float*       out   = (float*)d_out;

    // 61440 frames; 16 frames per 256-thread block (4 waves x 4 frames).
    dim3 grid(NFRAMES / 16), block(256);
    hipLaunchKernelGGL(ResidualEmbedding_70798240907390_kernel, grid, block, 0, stream,
                       bits, pcm, alpha, out);
}